// Round 7
// baseline (451.600 us; speedup 1.0000x reference)
//
#include <hip/hip_runtime.h>
#include <hip/hip_bf16.h>

// Problem constants: x[4,512,64,64], 32 groups, attention over 4096 spatial positions.
constexpr int BATCH = 4;
constexpr int CH    = 512;     // channels
constexpr int HWN   = 4096;    // h*w
constexpr int NG    = 32;      // groups
constexpr float SM_SCALE = 0.044194173824159216f; // 512^-0.5
constexpr float SM_L2E   = 0.06376608440f;        // SM_SCALE * log2(e)

// ---------------- static device workspace ----------------
__device__ __align__(256) ushort g_ht[(long)BATCH*HWN*CH];    // h_t[b][n][c]
__device__ __align__(256) ushort g_qk[(long)BATCH*HWN*1024];  // [b][n][0:512=q | 512:1024=k]
__device__ __align__(256) ushort g_v [(long)BATCH*CH*HWN];    // v[b][c][m]
__device__ __align__(256) ushort g_ot[(long)BATCH*HWN*CH];    // O_t[b][n][c]
__device__ __align__(256) ushort g_wqk[2*CH*CH];              // rows 0..511=wq, 512..1023=wk
__device__ __align__(256) ushort g_wv[CH*CH], g_wp[CH*CH];
__device__ float g_bqk[2*CH];
__device__ float g_mean[BATCH*NG], g_rstd[BATCH*NG];

typedef short v8s __attribute__((ext_vector_type(8)));
typedef float f32x4 __attribute__((ext_vector_type(4)));

__device__ inline ushort f2b(float f){
  __hip_bfloat16 h = __float2bfloat16(f);
  return __builtin_bit_cast(ushort, h);
}

__device__ inline void gload16(const ushort* g, ushort* lds_base){
  __builtin_amdgcn_global_load_lds(
      (const __attribute__((address_space(1))) unsigned int*)g,
      (__attribute__((address_space(3))) unsigned int*)lds_base, 16, 0, 0);
}

// ---------------- weight prep ----------------
__global__ __launch_bounds__(256) void prep_weights(const float* wq, const float* wk,
                                                    const float* wv, const float* wp,
                                                    const float* bq, const float* bk){
  int t = blockIdx.x*256 + threadIdx.x;   // < 262144
  g_wqk[t]        = f2b(wq[t]);
  g_wqk[CH*CH+t]  = f2b(wk[t]);
  g_wv[t] = f2b(wv[t]);
  g_wp[t] = f2b(wp[t]);
  if (t < 2*CH) g_bqk[t] = (t < CH) ? bq[t] : bk[t-CH];
}

// ---------------- GroupNorm stats ----------------
__global__ __launch_bounds__(256) void gn_stats(const float* x){
  __shared__ float ss[4], ss2[4];
  const float4* p = (const float4*)(x + (long)blockIdx.x*65536);
  float s = 0.f, s2 = 0.f;
  for (int i = threadIdx.x; i < 16384; i += 256){
    float4 v = p[i];
    s  += v.x + v.y + v.z + v.w;
    s2 += v.x*v.x + v.y*v.y + v.z*v.z + v.w*v.w;
  }
  for (int off = 1; off < 64; off <<= 1){
    s  += __shfl_xor(s,  off);
    s2 += __shfl_xor(s2, off);
  }
  if ((threadIdx.x & 63) == 0){ ss[threadIdx.x>>6] = s; ss2[threadIdx.x>>6] = s2; }
  __syncthreads();
  if (threadIdx.x == 0){
    float S1 = ss[0]+ss[1]+ss[2]+ss[3], S2 = ss2[0]+ss2[1]+ss2[2]+ss2[3];
    float mean = S1 * (1.0f/65536.0f);
    float var  = S2 * (1.0f/65536.0f) - mean*mean;
    g_mean[blockIdx.x] = mean;
    g_rstd[blockIdx.x] = rsqrtf(var + 1e-6f);
  }
}

// ---------------- GroupNorm apply + transpose ----------------
__global__ __launch_bounds__(256) void gn_apply(const float* x, const float* gamma, const float* beta){
  __shared__ ushort tile[64][72];
  const int b = blockIdx.z, tc = blockIdx.y, tn = blockIdx.x;
  const int t = threadIdx.x;
  const int r = t >> 4;
  const int ncol = (t & 15) * 4;
  const float* xb = x + ((long)b*CH + tc*64)*HWN + tn*64;
  #pragma unroll
  for (int rg = 0; rg < 4; rg++){
    int c_local = rg*16 + r;
    int c = tc*64 + c_local;
    int gidx = b*NG + (c >> 4);
    float mean = g_mean[gidx], rstd = g_rstd[gidx];
    float ga = gamma[c], be = beta[c];
    float4 v = *(const float4*)(xb + (long)c_local*HWN + ncol);
    tile[c_local][ncol+0] = f2b((v.x - mean)*rstd*ga + be);
    tile[c_local][ncol+1] = f2b((v.y - mean)*rstd*ga + be);
    tile[c_local][ncol+2] = f2b((v.z - mean)*rstd*ga + be);
    tile[c_local][ncol+3] = f2b((v.w - mean)*rstd*ga + be);
  }
  __syncthreads();
  ushort* ht = g_ht + ((long)b*HWN + tn*64)*CH + tc*64;
  #pragma unroll
  for (int rg = 0; rg < 4; rg++){
    int n_local = rg*16 + r;
    int cl = (t & 15) * 4;
    ushort4 pk;
    pk.x = tile[cl+0][n_local];
    pk.y = tile[cl+1][n_local];
    pk.z = tile[cl+2][n_local];
    pk.w = tile[cl+3][n_local];
    *(ushort4*)(ht + (long)n_local*CH + cl) = pk;
  }
}

// ---------------- 128^2 m97-style 2-phase GEMM ----------------
// CFG: 0=QK fused (A=h_t, Bt=wqk -> g_qk[n][1024], col bias g_bqk)
//      2=V        (A=wv, Bt=h_t -> v[c][m], row bias bv)
//      5=proj     (A=O_t, Bt=wp; out = x + c^T + bp)
template<int CFG>
__global__ __launch_bounds__(256, 2) void gemm_bt(const float* bias, const float* xres, float* outf){
  constexpr int Kdim = CH;

  __shared__ __align__(16) ushort As[128*32];
  __shared__ __align__(16) ushort Bs[128*32];

  const int z = blockIdx.z;
  const int tm = blockIdx.x, tn = blockIdx.y;
  const int t = threadIdx.x;

  const ushort *Ap, *Bp;  ushort* Cp = nullptr;
  long lda, ldb, ldc = 0;
  if constexpr (CFG==0){ Ap=g_ht+(long)z*HWN*CH; Bp=g_wqk; Cp=g_qk+(long)z*HWN*1024; lda=CH; ldb=CH; ldc=1024; }
  if constexpr (CFG==2){ Ap=g_wv; Bp=g_ht+(long)z*HWN*CH; Cp=g_v +(long)z*CH*HWN; lda=CH; ldb=CH; ldc=HWN; }
  if constexpr (CFG==5){ Ap=g_ot+(long)z*HWN*CH; Bp=g_wp; lda=CH; ldb=CH; }

  const int lane = t & 63, wid = t >> 6;
  const int wr = (wid >> 1) * 64, wc = (wid & 1) * 64;
  const int lr = lane & 15, lk = lane >> 4;

  const int srow = t >> 2, sko = t & 3;
  const int wave_base = (t & 192) * 8;

  f32x4 acc[4][4] = {};

  for (int kt = 0; kt < Kdim; kt += 32){
    __syncthreads();
    #pragma unroll
    for (int i = 0; i < 2; i++){
      int row = srow + i*64;
      const ushort* ga = Ap + (long)(tm*128 + row)*lda + kt + sko*8;
      const ushort* gb = Bp + (long)(tn*128 + row)*ldb + kt + sko*8;
      gload16(ga, As + wave_base + i*256*8);
      gload16(gb, Bs + wave_base + i*256*8);
    }
    __syncthreads();
    v8s af[4], bfr[4];
    #pragma unroll
    for (int mi = 0; mi < 4; mi++){
      int row = wr + mi*16 + lr;
      af[mi] = *(const v8s*)(As + row*32 + lk*8);
    }
    #pragma unroll
    for (int ni = 0; ni < 4; ni++){
      int row = wc + ni*16 + lr;
      bfr[ni] = *(const v8s*)(Bs + row*32 + lk*8);
    }
    #pragma unroll
    for (int mi = 0; mi < 4; mi++)
      #pragma unroll
      for (int ni = 0; ni < 4; ni++)
        acc[mi][ni] = __builtin_amdgcn_mfma_f32_16x16x32_bf16(af[mi], bfr[ni], acc[mi][ni], 0, 0, 0);
  }

  if constexpr (CFG==5){
    float* ob = outf + (long)z*CH*HWN;
    const float* xb = xres + (long)z*CH*HWN;
    #pragma unroll
    for (int mi = 0; mi < 4; mi++){
      #pragma unroll
      for (int ni = 0; ni < 4; ni++){
        int col = tn*128 + wc + ni*16 + lr;        // o
        int rowm = tm*128 + wr + mi*16 + lk*4;     // n
        float cb = bias[col];
        long off = (long)col*HWN + rowm;
        float4 xv = *(const float4*)(xb + off);
        float4 ov;
        ov.x = acc[mi][ni][0] + cb + xv.x;
        ov.y = acc[mi][ni][1] + cb + xv.y;
        ov.z = acc[mi][ni][2] + cb + xv.z;
        ov.w = acc[mi][ni][3] + cb + xv.w;
        *(float4*)(ob + off) = ov;
      }
    }
  } else {
    #pragma unroll
    for (int mi = 0; mi < 4; mi++){
      #pragma unroll
      for (int ni = 0; ni < 4; ni++){
        int col = tn*128 + wc + ni*16 + lr;
        float cb = 0.f;
        if constexpr (CFG==0) cb = g_bqk[col];
        #pragma unroll
        for (int j = 0; j < 4; j++){
          int rowm = tm*128 + wr + mi*16 + lk*4 + j;
          float v = acc[mi][ni][j];
          if constexpr (CFG==2) v += bias[rowm]; else v += cb;
          Cp[(long)rowm*ldc + col] = f2b(v);
        }
      }
    }
  }
}

// ---------------- fused attention: S = qk^T -> exp -> PV, no P in HBM -------------
// Per block: 64 q-rows (n-tile) x full KV=4096, KVT=32. 8 waves (512 thr), 1 blk/CU.
// Q in regs (16 v8s). K dbuf [2][32m][512c], V dbuf [2][512c][32m] via pre-swizzled
// global_load_lds (r5-verified involution: stored slot = want ^ (row&mask)).
// P bounced through 4KB swizzled LDS; O acc[4][4] f32x4 in regs; rowsum in regs.
// 2 raw barriers/iter: B1 = lgkmcnt(0) (P-writes visible), B2 = vmcnt(0) (stages
// landed; issued a full iter earlier so drain is cheap).
__global__ __launch_bounds__(512, 2) void fused_attn(){
  constexpr int NITER = HWN/32;  // 128
  __shared__ __align__(16) ushort Kl[2][32*512];  // 64 KB  (unit u=m*64+slot, 16B units)
  __shared__ __align__(16) ushort Vl[2][512*32];  // 64 KB  (unit u=c*4+slot)
  __shared__ __align__(16) ushort Pl[64*32];      // 4 KB   [n][m], slot^=(n&3)
  __shared__ float rs_lds[2][64];

  const int t = threadIdx.x, lane = t & 63, wid = t >> 6;
  const int lr = lane & 15, lk = lane >> 4;
  const int qn = wid >> 1, qm2 = wid & 1;     // QK wave split: n-range qn*16, m-range qm2*16
  const int ntile = blockIdx.x, z = blockIdx.y;
  const ushort* qk = g_qk + (long)z*HWN*1024;
  const ushort* vv = g_v  + (long)z*CH*HWN;

  // Q fragments for this wave's 16 n-rows, all 512 c (16 k-steps)
  v8s q[16];
  {
    const ushort* qrow = qk + (long)(ntile*64 + qn*16 + lr)*1024 + lk*8;
    #pragma unroll
    for (int s = 0; s < 16; s++) q[s] = *(const v8s*)(qrow + s*32);
  }

  auto stageK = [&](int kvt){
    ushort* dst = &Kl[kvt & 1][0] + wid*64*8;
    #pragma unroll
    for (int j = 0; j < 4; j++){
      int u = j*512 + t;
      int m = u >> 6, slot = u & 63;
      gload16(qk + 512 + (long)(kvt*32 + m)*1024 + 8*(slot ^ (m & 7)), dst + j*512*8);
    }
  };
  auto stageV = [&](int kvt){
    ushort* dst = &Vl[kvt & 1][0] + wid*64*8;
    #pragma unroll
    for (int j = 0; j < 4; j++){
      int u = j*512 + t;
      int c = u >> 2, slot = u & 3;
      gload16(vv + (long)c*HWN + kvt*32 + 8*(slot ^ (c & 3)), dst + j*512*8);
    }
  };

  stageK(0); stageV(0);
  asm volatile("s_waitcnt vmcnt(0)" ::: "memory");
  __builtin_amdgcn_s_barrier();

  f32x4 acc[4][4] = {};
  float rs4[4] = {0.f, 0.f, 0.f, 0.f};

  for (int kvt = 0; kvt < NITER; kvt++){
    if (kvt + 1 < NITER){ stageK(kvt+1); stageV(kvt+1); }
    const ushort* Kb = &Kl[kvt & 1][0];
    const ushort* Vb = &Vl[kvt & 1][0];

    // ---- QK: S[16n x 16m] for this wave; 4 indep chains for MFMA ILP ----
    f32x4 sc[4] = {};
    {
      const int mrow = qm2*16 + lr;                 // K row (= S col for this wave)
      __builtin_amdgcn_s_setprio(1);
      #pragma unroll
      for (int s = 0; s < 16; s++){
        v8s kf = *(const v8s*)(Kb + (mrow*64 + ((s*4 + lk) ^ (lr & 7)))*8);
        sc[s & 3] = __builtin_amdgcn_mfma_f32_16x16x32_bf16(q[s], kf, sc[s & 3], 0, 0, 0);
      }
      __builtin_amdgcn_s_setprio(0);
    }
    f32x4 sv = sc[0] + sc[1] + sc[2] + sc[3];

    // ---- exp -> P_lds (swizzled) + rowsum partials ----
    #pragma unroll
    for (int j = 0; j < 4; j++){
      float p = exp2f(sv[j] * SM_L2E);
      int n = qn*16 + lk*4 + j;
      int m = qm2*16 + lr;
      *(ushort*)((char*)Pl + n*64 + ((((m >> 3) ^ (n & 3)) << 4) | ((m & 7) * 2))) = f2b(p);
      rs4[j] += p;
    }

    asm volatile("s_waitcnt lgkmcnt(0)" ::: "memory");
    __builtin_amdgcn_s_barrier();                   // B1: P visible, K reads done

    // ---- PV: O[64n x 64c-chunk] += P * v^T ----
    {
      v8s pa[4], vb[4];
      #pragma unroll
      for (int fn = 0; fn < 4; fn++){
        int n = fn*16 + lr;
        pa[fn] = *(const v8s*)((char*)Pl + n*64 + ((lk ^ (n & 3)) << 4));
      }
      #pragma unroll
      for (int fc = 0; fc < 4; fc++){
        int c = wid*64 + fc*16 + lr;
        vb[fc] = *(const v8s*)(Vb + (c*4 + (lk ^ (c & 3)))*8);
      }
      __builtin_amdgcn_s_setprio(1);
      #pragma unroll
      for (int fn = 0; fn < 4; fn++)
        #pragma unroll
        for (int fc = 0; fc < 4; fc++)
          acc[fn][fc] = __builtin_amdgcn_mfma_f32_16x16x32_bf16(pa[fn], vb[fc], acc[fn][fc], 0, 0, 0);
      __builtin_amdgcn_s_setprio(0);
    }

    asm volatile("s_waitcnt vmcnt(0)" ::: "memory");
    __builtin_amdgcn_s_barrier();                   // B2: next-iter stages landed, bufs free
  }

  // ---- rowsum reduce across lanes + partner wave ----
  #pragma unroll
  for (int j = 0; j < 4; j++){
    float s = rs4[j];
    s += __shfl_xor(s, 1); s += __shfl_xor(s, 2);
    s += __shfl_xor(s, 4); s += __shfl_xor(s, 8);
    rs4[j] = s;
  }
  if (lr == 0){
    #pragma unroll
    for (int j = 0; j < 4; j++)
      rs_lds[qm2][qn*16 + lk*4 + j] = rs4[j];
  }
  __syncthreads();

  // ---- O write: O_t[b][n][c] = acc / rowsum[n] ----
  ushort* ot = g_ot + ((long)z*HWN + ntile*64)*CH;
  #pragma unroll
  for (int fn = 0; fn < 4; fn++){
    #pragma unroll
    for (int j = 0; j < 4; j++){
      int n = fn*16 + lk*4 + j;
      float inv = 1.0f / (rs_lds[0][n] + rs_lds[1][n]);
      #pragma unroll
      for (int fc = 0; fc < 4; fc++){
        int c = wid*64 + fc*16 + lr;
        ot[(long)n*CH + c] = f2b(acc[fn][fc][j] * inv);
      }
    }
  }
}

extern "C" void kernel_launch(void* const* d_in, const int* in_sizes, int n_in,
                              void* d_out, int out_size, void* d_ws, size_t ws_size,
                              hipStream_t stream){
  const float* x     = (const float*)d_in[0];
  const float* gamma = (const float*)d_in[1];
  const float* beta  = (const float*)d_in[2];
  const float* wq    = (const float*)d_in[3];
  const float* bq    = (const float*)d_in[4];
  const float* wk    = (const float*)d_in[5];
  const float* bk    = (const float*)d_in[6];
  const float* wv    = (const float*)d_in[7];
  const float* bv    = (const float*)d_in[8];
  const float* wp    = (const float*)d_in[9];
  const float* bp    = (const float*)d_in[10];
  float* out = (float*)d_out;

  prep_weights<<<1024, 256, 0, stream>>>(wq, wk, wv, wp, bq, bk);
  gn_stats<<<BATCH*NG, 256, 0, stream>>>(x);
  gn_apply<<<dim3(HWN/64, CH/64, BATCH), 256, 0, stream>>>(x, gamma, beta);

  gemm_bt<0><<<dim3(HWN/128, 1024/128, BATCH), 256, 0, stream>>>(nullptr, nullptr, nullptr); // q|k
  gemm_bt<2><<<dim3(CH/128, HWN/128, BATCH), 256, 0, stream>>>(bv, nullptr, nullptr);        // v
  fused_attn<<<dim3(HWN/64, BATCH), 512, 0, stream>>>();                                     // S+exp+PV
  gemm_bt<5><<<dim3(HWN/128, CH/128, BATCH), 256, 0, stream>>>(bp, x, out);                  // out
}